// Round 1
// baseline (24543.898 us; speedup 1.0000x reference)
//
#include <hip/hip_runtime.h>
#include <cstdint>
#include <cmath>

// ---------------- problem constants ----------------
#define DD      768
#define FFD     3072
#define NH      12
#define HDIM    64
#define LAYERS  3
#define CSZ     512
#define NB      256
#define NC      32
#define NSEQ    (NB * NC * 2)   // 16384 sequences
#define NTOK    (NSEQ * 2)      // 32768 token rows
#define CHROWS  4096            // token rows per chunk
#define NCHUNK  (NTOK / CHROWS) // 8
#define CHSEQ   (CHROWS / 2)    // 2048 sequences per chunk

static __device__ __forceinline__ float gelu_f(float x) {
    // exact gelu: x * 0.5 * (1 + erf(x/sqrt(2)))
    return 0.5f * x * (1.0f + erff(x * 0.70710678118654752f));
}

static __device__ __forceinline__ float wave_sum64(float v) {
#pragma unroll
    for (int off = 32; off > 0; off >>= 1) v += __shfl_xor(v, off, 64);
    return v;
}

// ---------------- build x0: [32768][768] ----------------
// row r: n=r>>1 q=r&1 ; n = ((i*32+k)*2+j) ; q==0 -> parent[i], q==1 -> child[i,k,1-j]
__global__ __launch_bounds__(192) void build_x(const float* __restrict__ parent,
                                               const float* __restrict__ child,
                                               float* __restrict__ X) {
    const int r = blockIdx.x;
    const int t = threadIdx.x;        // 192 threads * float4 = 768
    const int n = r >> 1, q = r & 1;
    const int i = n >> 6;
    const int k = (n >> 1) & 31;
    const int j = n & 1;
    const float* src = (q == 0) ? (parent + (size_t)i * DD)
                                : (child + ((size_t)((i * 32 + k) * 2 + (1 - j))) * DD);
    ((float4*)(X + (size_t)r * DD))[t] = ((const float4*)src)[t];
}

// ---------------- generic NT GEMM ----------------
// C[M x N] = A[M x K](lda) @ W[N x K]^T + bias, optional exact-gelu epilogue.
// N multiple of 128, K multiple of 16; M guarded. 128x128x16 tile, 8x8/thread.
__global__ __launch_bounds__(256) void gemm_nt(const float* __restrict__ A, int lda,
                                               const float* __restrict__ W,
                                               const float* __restrict__ bias,
                                               float* __restrict__ C, int ldc,
                                               int M, int K, int dogelu) {
    __shared__ float As[16][132];
    __shared__ float Bs[16][132];
    const int tid = threadIdx.x;
    const int m0 = blockIdx.y * 128;
    const int n0 = blockIdx.x * 128;
    const int lr = tid >> 1;          // 0..127 tile row
    const int lk = (tid & 1) * 8;     // 0 or 8
    const int tx = tid & 15;
    const int ty = tid >> 4;

    float acc[8][8];
#pragma unroll
    for (int i = 0; i < 8; ++i)
#pragma unroll
        for (int j = 0; j < 8; ++j) acc[i][j] = 0.0f;

    const int gm = m0 + lr;
    const bool avalid = (gm < M);
    const float* Aptr = A + (size_t)gm * lda + lk;
    const float* Wptr = W + (size_t)(n0 + lr) * K + lk;

    for (int k0 = 0; k0 < K; k0 += 16) {
        float4 a0 = make_float4(0.f, 0.f, 0.f, 0.f), a1 = a0;
        if (avalid) {
            a0 = *(const float4*)(Aptr + k0);
            a1 = *(const float4*)(Aptr + k0 + 4);
        }
        const float4 w0 = *(const float4*)(Wptr + k0);
        const float4 w1 = *(const float4*)(Wptr + k0 + 4);
        __syncthreads();
        As[lk + 0][lr] = a0.x; As[lk + 1][lr] = a0.y; As[lk + 2][lr] = a0.z; As[lk + 3][lr] = a0.w;
        As[lk + 4][lr] = a1.x; As[lk + 5][lr] = a1.y; As[lk + 6][lr] = a1.z; As[lk + 7][lr] = a1.w;
        Bs[lk + 0][lr] = w0.x; Bs[lk + 1][lr] = w0.y; Bs[lk + 2][lr] = w0.z; Bs[lk + 3][lr] = w0.w;
        Bs[lk + 4][lr] = w1.x; Bs[lk + 5][lr] = w1.y; Bs[lk + 6][lr] = w1.z; Bs[lk + 7][lr] = w1.w;
        __syncthreads();
#pragma unroll
        for (int kk = 0; kk < 16; ++kk) {
            float a[8], b[8];
            *(float4*)&a[0] = *(const float4*)&As[kk][ty * 8];
            *(float4*)&a[4] = *(const float4*)&As[kk][ty * 8 + 4];
            *(float4*)&b[0] = *(const float4*)&Bs[kk][tx * 8];
            *(float4*)&b[4] = *(const float4*)&Bs[kk][tx * 8 + 4];
#pragma unroll
            for (int i = 0; i < 8; ++i)
#pragma unroll
                for (int j = 0; j < 8; ++j) acc[i][j] = fmaf(a[i], b[j], acc[i][j]);
        }
    }

    float bn[8];
    if (bias) {
        const float4 b0 = *(const float4*)(bias + n0 + tx * 8);
        const float4 b1 = *(const float4*)(bias + n0 + tx * 8 + 4);
        bn[0] = b0.x; bn[1] = b0.y; bn[2] = b0.z; bn[3] = b0.w;
        bn[4] = b1.x; bn[5] = b1.y; bn[6] = b1.z; bn[7] = b1.w;
    } else {
#pragma unroll
        for (int j = 0; j < 8; ++j) bn[j] = 0.0f;
    }
#pragma unroll
    for (int i = 0; i < 8; ++i) {
        const int m = m0 + ty * 8 + i;
        if (m < M) {
            float o[8];
#pragma unroll
            for (int j = 0; j < 8; ++j) o[j] = acc[i][j] + bn[j];
            if (dogelu) {
#pragma unroll
                for (int j = 0; j < 8; ++j) o[j] = gelu_f(o[j]);
            }
            float4 s0 = make_float4(o[0], o[1], o[2], o[3]);
            float4 s1 = make_float4(o[4], o[5], o[6], o[7]);
            *(float4*)(C + (size_t)m * ldc + n0 + tx * 8) = s0;
            *(float4*)(C + (size_t)m * ldc + n0 + tx * 8 + 4) = s1;
        }
    }
}

// ---------------- attention (seq len 2), one wave per (sequence, head) ----------------
// QKV: [CHROWS][2304] rows = tokens of this chunk (seq-major, 2 rows per seq)
// peq/pek: [3][768] = pos_emb roles {0,1,2} projected through Wq/Wk (no bias)
__global__ __launch_bounds__(256) void attn_kernel(const float* __restrict__ QKV,
                                                   const float* __restrict__ peq,
                                                   const float* __restrict__ pek,
                                                   float* __restrict__ O,
                                                   int seq0) {
    const int wid = threadIdx.x >> 6;
    const int lane = threadIdx.x & 63;
    const int task = blockIdx.x * 4 + wid;     // CHSEQ*NH tasks
    const int ns = task / NH;                  // local sequence
    const int h = task - ns * NH;
    const int j = (seq0 + ns) & 1;
    const float* base = QKV + (size_t)(2 * ns) * (3 * DD);
    const int c = h * HDIM + lane;
    const int role1 = (1 + j) * DD;

    const float q0 = base[c] + peq[c];
    const float k0 = base[DD + c] + pek[c];
    const float v0 = base[2 * DD + c];
    const float* base1 = base + 3 * DD;
    const float q1 = base1[c] + peq[role1 + c];
    const float k1 = base1[DD + c] + pek[role1 + c];
    const float v1 = base1[2 * DD + c];

    float p00 = q0 * k0, p01 = q0 * k1, p10 = q1 * k0, p11 = q1 * k1;
#pragma unroll
    for (int off = 32; off > 0; off >>= 1) {
        p00 += __shfl_xor(p00, off, 64);
        p01 += __shfl_xor(p01, off, 64);
        p10 += __shfl_xor(p10, off, 64);
        p11 += __shfl_xor(p11, off, 64);
    }
    const float sc = 0.125f;  // 1/sqrt(64)
    const float s00 = p00 * sc, s01 = p01 * sc, s10 = p10 * sc, s11 = p11 * sc;

    const float m0 = fmaxf(s00, s01);
    const float e00 = expf(s00 - m0), e01 = expf(s01 - m0);
    const float a00 = e00 / (e00 + e01);
    const float o0 = a00 * v0 + (1.0f - a00) * v1;

    const float m1 = fmaxf(s10, s11);
    const float e10 = expf(s10 - m1), e11 = expf(s11 - m1);
    const float a10 = e10 / (e10 + e11);
    const float o1 = a10 * v0 + (1.0f - a10) * v1;

    O[(size_t)(2 * ns) * DD + c] = o0;
    O[(size_t)(2 * ns + 1) * DD + c] = o1;
}

// ---------------- x = inorm(x + d), row-wise over 768 ----------------
__global__ __launch_bounds__(256) void add_inorm(float* __restrict__ x,
                                                 const float* __restrict__ d) {
    const int r = blockIdx.x;
    float* xr = x + (size_t)r * DD;
    const float* dr = d + (size_t)r * DD;
    const int t = threadIdx.x;
    float v[3];
    float s = 0.f, ss = 0.f;
#pragma unroll
    for (int i = 0; i < 3; ++i) {
        const float val = xr[t + i * 256] + dr[t + i * 256];
        v[i] = val; s += val; ss += val * val;
    }
    s = wave_sum64(s); ss = wave_sum64(ss);
    __shared__ float red[8];
    const int w = t >> 6;
    if ((t & 63) == 0) { red[w] = s; red[4 + w] = ss; }
    __syncthreads();
    s = red[0] + red[1] + red[2] + red[3];
    ss = red[4] + red[5] + red[6] + red[7];
    const float mean = s * (1.0f / DD);
    const float var = ss * (1.0f / DD) - mean * mean;
    const float rs = rsqrtf(var + 1e-5f);
#pragma unroll
    for (int i = 0; i < 3; ++i) xr[t + i * 256] = (v[i] - mean) * rs;
}

// ---------------- final: out[n] = inorm(x[2n] + x[2n+1]) ----------------
__global__ __launch_bounds__(256) void final_inorm(const float* __restrict__ x,
                                                   float* __restrict__ out) {
    const int n = blockIdx.x;
    const float* r0 = x + (size_t)(2 * n) * DD;
    const float* r1 = r0 + DD;
    const int t = threadIdx.x;
    float v[3];
    float s = 0.f, ss = 0.f;
#pragma unroll
    for (int i = 0; i < 3; ++i) {
        const float val = r0[t + i * 256] + r1[t + i * 256];
        v[i] = val; s += val; ss += val * val;
    }
    s = wave_sum64(s); ss = wave_sum64(ss);
    __shared__ float red[8];
    const int w = t >> 6;
    if ((t & 63) == 0) { red[w] = s; red[4 + w] = ss; }
    __syncthreads();
    s = red[0] + red[1] + red[2] + red[3];
    ss = red[4] + red[5] + red[6] + red[7];
    const float mean = s * (1.0f / DD);
    const float var = ss * (1.0f / DD) - mean * mean;
    const float rs = rsqrtf(var + 1e-5f);
#pragma unroll
    for (int i = 0; i < 3; ++i) out[(size_t)n * DD + t + i * 256] = (v[i] - mean) * rs;
}

// ---------------- scores: out[row*2+which] = dot(pc[row>>5], cc[row]) / sqrt(CS) ----------------
__global__ __launch_bounds__(256) void score_dot(const float* __restrict__ pc,
                                                 const float* __restrict__ cc,
                                                 float* __restrict__ out,
                                                 int row0, int which) {
    const int wid = threadIdx.x >> 6;
    const int lane = threadIdx.x & 63;
    const int lrow = blockIdx.x * 4 + wid;
    const int row = row0 + lrow;
    const int b = row >> 5;
    const float* p = pc + (size_t)b * CSZ;
    const float* c = cc + (size_t)lrow * CSZ;
    float s = 0.f;
#pragma unroll
    for (int e = 0; e < 8; ++e) s += p[e * 64 + lane] * c[e * 64 + lane];
    s = wave_sum64(s);
    if (lane == 0) out[row * 2 + which] = s * 0.04419417382415922f; // 1/sqrt(512)
}

// ---------------- host launch ----------------
extern "C" void kernel_launch(void* const* d_in, const int* in_sizes, int n_in,
                              void* d_out, int out_size, void* d_ws, size_t ws_size,
                              hipStream_t stream) {
    const float* parent = (const float*)d_in[0];
    const float* child  = (const float*)d_in[1];
    // d_in[2] parent_scores, d_in[3] child_scores: unused by the reference
    const float* aiw = (const float*)d_in[4];
    const float* aib = (const float*)d_in[5];
    const float* aow = (const float*)d_in[6];
    const float* aob = (const float*)d_in[7];
    const float* l1w = (const float*)d_in[8];
    const float* l1b = (const float*)d_in[9];
    const float* l2w = (const float*)d_in[10];
    const float* l2b = (const float*)d_in[11];
    const float* pemb = (const float*)d_in[12];
    const float* pw1 = (const float*)d_in[13];
    const float* pb1 = (const float*)d_in[14];
    const float* pw2 = (const float*)d_in[15];
    const float* pb2 = (const float*)d_in[16];
    const float* lw1 = (const float*)d_in[17];
    const float* lb1 = (const float*)d_in[18];
    const float* lw2 = (const float*)d_in[19];
    const float* lb2 = (const float*)d_in[20];
    const float* rw1 = (const float*)d_in[21];
    const float* rb1 = (const float*)d_in[22];
    const float* rw2 = (const float*)d_in[23];
    const float* rb2 = (const float*)d_in[24];
    float* out = (float*)d_out;

    // workspace layout (floats): total ~44.4M floats = ~178 MB
    float* X   = (float*)d_ws;                      // [32768][768]
    float* S1  = X  + (size_t)NTOK * DD;            // [4096][3072] chunk scratch
    float* S2  = S1 + (size_t)CHROWS * FFD;         // [4096][768]
    float* S3  = S2 + (size_t)CHROWS * DD;          // [4096][768]
    float* P1  = S3 + (size_t)CHROWS * DD;          // [256][768]
    float* P2  = P1 + (size_t)256 * DD;             // [256][512]
    float* PEQ = P2 + (size_t)256 * CSZ;            // [3][768] (+pad)
    float* PEK = PEQ + 4 * DD;                      // [3][768] (+pad)
    (void)ws_size; (void)in_sizes; (void)n_in; (void)out_size;

    auto gemm = [&](const float* A, int lda, const float* W, const float* bias,
                    float* C, int ldc, int M, int N, int K, int dg) {
        dim3 grid(N / 128, (M + 127) / 128);
        gemm_nt<<<grid, 256, 0, stream>>>(A, lda, W, bias, C, ldc, M, K, dg);
    };

    // ---- build x0 ----
    build_x<<<NTOK, 192, 0, stream>>>(parent, child, X);

    // ---- outside scores ----
    gemm(parent, DD, pw1, pb1, P1, DD, 256, DD, DD, 1);
    gemm(P1, DD, pw2, pb2, P2, CSZ, 256, CSZ, DD, 0);
    for (int sc = 0; sc < 2; ++sc) {
        const int r0 = sc * 4096;  // (b,c) row offset
        // lc = MLP_left(child[:,:,0,:]) -> right_score (which=1)
        gemm(child + (size_t)r0 * 2 * DD, 2 * DD, lw1, lb1, S1, DD, 4096, DD, DD, 1);
        gemm(S1, DD, lw2, lb2, S2, CSZ, 4096, CSZ, DD, 0);
        score_dot<<<1024, 256, 0, stream>>>(P2, S2, out, r0, 1);
        // rc = MLP_right(child[:,:,1,:]) -> left_score (which=0)
        gemm(child + (size_t)r0 * 2 * DD + DD, 2 * DD, rw1, rb1, S1, DD, 4096, DD, DD, 1);
        gemm(S1, DD, rw2, rb2, S2, CSZ, 4096, CSZ, DD, 0);
        score_dot<<<1024, 256, 0, stream>>>(P2, S2, out, r0, 0);
    }

    // ---- transformer layers ----
    for (int l = 0; l < LAYERS; ++l) {
        const float* Wl  = aiw + (size_t)l * 3 * DD * DD;
        const float* bl  = aib + (size_t)l * 3 * DD;
        const float* owl = aow + (size_t)l * DD * DD;
        const float* obl = aob + (size_t)l * DD;
        const float* w1l = l1w + (size_t)l * FFD * DD;
        const float* b1l = l1b + (size_t)l * FFD;
        const float* w2l = l2w + (size_t)l * DD * FFD;
        const float* b2l = l2b + (size_t)l * DD;
        const float* pel = pemb + (size_t)l * 4 * DD;

        // pe projections through Wq / Wk (roles 0..2, no bias)
        gemm(pel, DD, Wl, nullptr, PEQ, DD, 3, DD, DD, 0);
        gemm(pel, DD, Wl + (size_t)DD * DD, nullptr, PEK, DD, 3, DD, DD, 0);

        for (int c = 0; c < NCHUNK; ++c) {
            const int r0 = c * CHROWS;
            float* Xc = X + (size_t)r0 * DD;
            // QKV = x @ Wqkv^T + b  -> S1 [4096][2304]
            gemm(Xc, DD, Wl, bl, S1, 3 * DD, CHROWS, 3 * DD, DD, 0);
            // attention -> S2 [4096][768]
            attn_kernel<<<CHSEQ * NH / 4, 256, 0, stream>>>(S1, PEQ, PEK, S2, c * CHSEQ);
            // out-proj -> S3
            gemm(S2, DD, owl, obl, S3, DD, CHROWS, DD, DD, 0);
            add_inorm<<<CHROWS, 256, 0, stream>>>(Xc, S3);
            // FFN
            gemm(Xc, DD, w1l, b1l, S1, FFD, CHROWS, FFD, DD, 1);
            gemm(S1, FFD, w2l, b2l, S2, DD, CHROWS, DD, FFD, 0);
            add_inorm<<<CHROWS, 256, 0, stream>>>(Xc, S2);
        }
    }

    // ---- final: inorm over token-sum ----
    final_inorm<<<NSEQ, 256, 0, stream>>>(X, out + NSEQ);
}

// Round 2
// 3504.455 us; speedup vs baseline: 7.0036x; 7.0036x over previous
//
#include <hip/hip_runtime.h>
#include <cstdint>
#include <cmath>

// ---------------- problem constants ----------------
#define DD      768
#define FFD     3072
#define NH      12
#define HDIM    64
#define LAYERS  3
#define CSZ     512
#define NB      256
#define NC      32
#define NSEQ    (NB * NC * 2)   // 16384 sequences
#define NTOK    (NSEQ * 2)      // 32768 token rows
#define CHROWS  8192            // token rows per chunk
#define NCHUNK  (NTOK / CHROWS) // 4
#define CHSEQ   (CHROWS / 2)    // 4096 sequences per chunk

typedef unsigned short ushort_t;
using short8 = __attribute__((ext_vector_type(8))) short;
using f32x4  = __attribute__((ext_vector_type(4))) float;

static __device__ __forceinline__ float b2f(ushort_t u) {
    union { float f; uint32_t i; } x; x.i = ((uint32_t)u) << 16; return x.f;
}
static __device__ __forceinline__ ushort_t f2b(float f) {
    uint32_t i = __float_as_uint(f);
    uint32_t r = (i + 0x7fffu + ((i >> 16) & 1u)) >> 16;   // RNE
    return (ushort_t)r;
}
static __device__ __forceinline__ float gelu_f(float x) {
    return 0.5f * x * (1.0f + erff(x * 0.70710678118654752f));
}
static __device__ __forceinline__ float wave_sum64(float v) {
#pragma unroll
    for (int off = 32; off > 0; off >>= 1) v += __shfl_xor(v, off, 64);
    return v;
}
static __device__ __forceinline__ void async_cp16(const void* g, void* l) {
    __builtin_amdgcn_global_load_lds((const __attribute__((address_space(1))) void*)g,
                                     (__attribute__((address_space(3))) void*)l, 16, 0, 0);
}

// ---------------- fp32 -> bf16 convert (n % 4 == 0) ----------------
__global__ __launch_bounds__(256) void cvt_bf16(const float* __restrict__ s,
                                                ushort_t* __restrict__ d, int n) {
    const int i = (blockIdx.x * 256 + threadIdx.x) * 4;
    if (i < n) {
        const float4 v = *(const float4*)(s + i);
        ushort4 o;
        o.x = f2b(v.x); o.y = f2b(v.y); o.z = f2b(v.z); o.w = f2b(v.w);
        *(ushort4*)(d + i) = o;
    }
}

// ---------------- build x0 (bf16): [32768][768] ----------------
__global__ __launch_bounds__(192) void build_x(const float* __restrict__ parent,
                                               const float* __restrict__ child,
                                               ushort_t* __restrict__ X) {
    const int r = blockIdx.x;
    const int t = threadIdx.x;        // 192 threads * 4 = 768
    const int n = r >> 1, q = r & 1;
    const int i = n >> 6;
    const int k = (n >> 1) & 31;
    const int j = n & 1;
    const float* src = (q == 0) ? (parent + (size_t)i * DD)
                                : (child + ((size_t)((i * 32 + k) * 2 + (1 - j))) * DD);
    const float4 v = ((const float4*)src)[t];
    ushort4 o;
    o.x = f2b(v.x); o.y = f2b(v.y); o.z = f2b(v.z); o.w = f2b(v.w);
    ((ushort4*)(X + (size_t)r * DD))[t] = o;
}

// ---------------- bf16 MFMA NT GEMM (m97 structure) ----------------
// C[M x N](bf16) = gelu?( A[M x K](bf16, lda) @ W[N x K]^T + bias(f32) )
// M,N multiples of 128; K multiple of 32. 128x128x32 tile, 4 waves, 4x4 MFMA each.
__global__ __launch_bounds__(256) void gemm_bf16(const ushort_t* __restrict__ A, int lda,
                                                 const ushort_t* __restrict__ W,
                                                 const float* __restrict__ bias,
                                                 ushort_t* __restrict__ C, int ldc,
                                                 int K, int dogelu) {
    __shared__ __align__(16) short As[128 * 32];
    __shared__ __align__(16) short Bs[128 * 32];
    const int tid = threadIdx.x;
    const int m0 = blockIdx.y * 128;
    const int n0 = blockIdx.x * 128;

    // staging: idx in [0,512), row = idx>>2, col8 = (idx&3)*8 ; lds = idx*8 elems
    const int r0s = tid >> 2, c0s = (tid & 3) * 8;
    const ushort_t* Ag0 = A + (size_t)(m0 + r0s) * lda + c0s;
    const ushort_t* Ag1 = A + (size_t)(m0 + 64 + r0s) * lda + c0s;
    const ushort_t* Wg0 = W + (size_t)(n0 + r0s) * K + c0s;
    const ushort_t* Wg1 = W + (size_t)(n0 + 64 + r0s) * K + c0s;
    short* Al0 = As + tid * 8;
    short* Al1 = As + (256 + tid) * 8;
    short* Bl0 = Bs + tid * 8;
    short* Bl1 = Bs + (256 + tid) * 8;

    const int wid = tid >> 6, lane = tid & 63;
    const int wm = (wid >> 1) * 64, wn = (wid & 1) * 64;
    const int lm = lane & 15;
    const int ko = (lane >> 4) * 8;

    f32x4 acc[4][4];
#pragma unroll
    for (int i = 0; i < 4; ++i)
#pragma unroll
        for (int j = 0; j < 4; ++j) acc[i][j] = {0.f, 0.f, 0.f, 0.f};

    for (int k0 = 0; k0 < K; k0 += 32) {
        __syncthreads();                 // previous iter's LDS reads done
        async_cp16(Ag0 + k0, Al0);
        async_cp16(Ag1 + k0, Al1);
        async_cp16(Wg0 + k0, Bl0);
        async_cp16(Wg1 + k0, Bl1);
        __syncthreads();                 // drains vmcnt, LDS ready

        short8 af[4], bfr[4];
#pragma unroll
        for (int i = 0; i < 4; ++i)
            af[i] = *(const short8*)(As + (wm + i * 16 + lm) * 32 + ko);
#pragma unroll
        for (int j = 0; j < 4; ++j)
            bfr[j] = *(const short8*)(Bs + (wn + j * 16 + lm) * 32 + ko);
#pragma unroll
        for (int i = 0; i < 4; ++i)
#pragma unroll
            for (int j = 0; j < 4; ++j)
                acc[i][j] = __builtin_amdgcn_mfma_f32_16x16x32_bf16(af[i], bfr[j], acc[i][j], 0, 0, 0);
    }

    // epilogue: col = lane&15, row = (lane>>4)*4 + reg
    const int cn = n0 + wn + lm;
    const int rb = m0 + wm + (lane >> 4) * 4;
#pragma unroll
    for (int j = 0; j < 4; ++j) {
        const int col = cn + j * 16;
        const float bj = bias ? bias[col] : 0.0f;
#pragma unroll
        for (int i = 0; i < 4; ++i) {
#pragma unroll
            for (int r = 0; r < 4; ++r) {
                float v = acc[i][j][r] + bj;
                if (dogelu) v = gelu_f(v);
                C[(size_t)(rb + i * 16 + r) * ldc + col] = f2b(v);
            }
        }
    }
}

// ---------------- pe projections: PEQ/PEK[r][o] = dot(pe[r], Wq/Wk[o]) ----------------
// fp32 inputs/outputs; one wave per output element; 2*3*768 = 4608 outputs
__global__ __launch_bounds__(256) void pe_proj(const float* __restrict__ pel,   // [4][768]
                                               const float* __restrict__ aiwl,  // [2304][768]
                                               float* __restrict__ PEQ,         // [3][768]
                                               float* __restrict__ PEK) {
    const int wid = threadIdx.x >> 6, lane = threadIdx.x & 63;
    const int task = blockIdx.x * 4 + wid;        // 0..4607
    const int which = task >= 3 * DD;
    const int idx = task - which * 3 * DD;
    const int r = idx / DD, o = idx - r * DD;
    const float* pe = pel + (size_t)r * DD;
    const float* w = aiwl + (size_t)(which ? DD + o : o) * DD;
    float s = 0.f;
#pragma unroll
    for (int e = 0; e < 12; ++e) s += pe[e * 64 + lane] * w[e * 64 + lane];
    s = wave_sum64(s);
    if (lane == 0) (which ? PEK : PEQ)[r * DD + o] = s;
}

// ---------------- attention (seq len 2), one wave per (sequence, head) ----------------
__global__ __launch_bounds__(256) void attn_kernel(const ushort_t* __restrict__ QKV, // [CHROWS][2304] bf16
                                                   const float* __restrict__ peq,
                                                   const float* __restrict__ pek,
                                                   ushort_t* __restrict__ O,         // [CHROWS][768] bf16
                                                   int seq0) {
    const int wid = threadIdx.x >> 6;
    const int lane = threadIdx.x & 63;
    const int task = blockIdx.x * 4 + wid;     // CHSEQ*NH tasks
    const int ns = task / NH;
    const int h = task - ns * NH;
    const int j = (seq0 + ns) & 1;
    const ushort_t* base = QKV + (size_t)(2 * ns) * (3 * DD);
    const int c = h * HDIM + lane;
    const int role1 = (1 + j) * DD;

    const float q0 = b2f(base[c]) + peq[c];
    const float k0 = b2f(base[DD + c]) + pek[c];
    const float v0 = b2f(base[2 * DD + c]);
    const ushort_t* base1 = base + 3 * DD;
    const float q1 = b2f(base1[c]) + peq[role1 + c];
    const float k1 = b2f(base1[DD + c]) + pek[role1 + c];
    const float v1 = b2f(base1[2 * DD + c]);

    float p00 = q0 * k0, p01 = q0 * k1, p10 = q1 * k0, p11 = q1 * k1;
#pragma unroll
    for (int off = 32; off > 0; off >>= 1) {
        p00 += __shfl_xor(p00, off, 64);
        p01 += __shfl_xor(p01, off, 64);
        p10 += __shfl_xor(p10, off, 64);
        p11 += __shfl_xor(p11, off, 64);
    }
    const float sc = 0.125f;
    const float s00 = p00 * sc, s01 = p01 * sc, s10 = p10 * sc, s11 = p11 * sc;

    const float m0 = fmaxf(s00, s01);
    const float e00 = __expf(s00 - m0), e01 = __expf(s01 - m0);
    const float a00 = e00 / (e00 + e01);
    const float o0 = a00 * v0 + (1.0f - a00) * v1;

    const float m1 = fmaxf(s10, s11);
    const float e10 = __expf(s10 - m1), e11 = __expf(s11 - m1);
    const float a10 = e10 / (e10 + e11);
    const float o1 = a10 * v0 + (1.0f - a10) * v1;

    O[(size_t)(2 * ns) * DD + c] = f2b(o0);
    O[(size_t)(2 * ns + 1) * DD + c] = f2b(o1);
}

// ---------------- x = inorm(x + d), bf16 in/out, one wave per row ----------------
__global__ __launch_bounds__(256) void add_inorm(ushort_t* __restrict__ x,
                                                 const ushort_t* __restrict__ d) {
    const int wid = threadIdx.x >> 6, lane = threadIdx.x & 63;
    const int r = blockIdx.x * 4 + wid;
    ushort_t* xr = x + (size_t)r * DD;
    const ushort_t* dr = d + (size_t)r * DD;
    float v[12];
    float s = 0.f, ss = 0.f;
#pragma unroll
    for (int e = 0; e < 3; ++e) {
        const ushort4 xa = ((const ushort4*)xr)[e * 64 + lane];
        const ushort4 da = ((const ushort4*)dr)[e * 64 + lane];
        const float a0 = b2f(xa.x) + b2f(da.x);
        const float a1 = b2f(xa.y) + b2f(da.y);
        const float a2 = b2f(xa.z) + b2f(da.z);
        const float a3 = b2f(xa.w) + b2f(da.w);
        v[e * 4 + 0] = a0; v[e * 4 + 1] = a1; v[e * 4 + 2] = a2; v[e * 4 + 3] = a3;
        s += a0 + a1 + a2 + a3;
        ss += a0 * a0 + a1 * a1 + a2 * a2 + a3 * a3;
    }
    s = wave_sum64(s); ss = wave_sum64(ss);
    const float mean = s * (1.0f / DD);
    const float var = ss * (1.0f / DD) - mean * mean;
    const float rs = rsqrtf(var + 1e-5f);
#pragma unroll
    for (int e = 0; e < 3; ++e) {
        ushort4 o;
        o.x = f2b((v[e * 4 + 0] - mean) * rs);
        o.y = f2b((v[e * 4 + 1] - mean) * rs);
        o.z = f2b((v[e * 4 + 2] - mean) * rs);
        o.w = f2b((v[e * 4 + 3] - mean) * rs);
        ((ushort4*)xr)[e * 64 + lane] = o;
    }
}

// ---------------- final: out[n] = inorm(x[2n] + x[2n+1]) fp32 out, wave per row ----------------
__global__ __launch_bounds__(256) void final_inorm(const ushort_t* __restrict__ x,
                                                   float* __restrict__ out) {
    const int wid = threadIdx.x >> 6, lane = threadIdx.x & 63;
    const int n = blockIdx.x * 4 + wid;
    const ushort_t* r0 = x + (size_t)(2 * n) * DD;
    const ushort_t* r1 = r0 + DD;
    float v[12];
    float s = 0.f, ss = 0.f;
#pragma unroll
    for (int e = 0; e < 3; ++e) {
        const ushort4 xa = ((const ushort4*)r0)[e * 64 + lane];
        const ushort4 xb = ((const ushort4*)r1)[e * 64 + lane];
        const float a0 = b2f(xa.x) + b2f(xb.x);
        const float a1 = b2f(xa.y) + b2f(xb.y);
        const float a2 = b2f(xa.z) + b2f(xb.z);
        const float a3 = b2f(xa.w) + b2f(xb.w);
        v[e * 4 + 0] = a0; v[e * 4 + 1] = a1; v[e * 4 + 2] = a2; v[e * 4 + 3] = a3;
        s += a0 + a1 + a2 + a3;
        ss += a0 * a0 + a1 * a1 + a2 * a2 + a3 * a3;
    }
    s = wave_sum64(s); ss = wave_sum64(ss);
    const float mean = s * (1.0f / DD);
    const float var = ss * (1.0f / DD) - mean * mean;
    const float rs = rsqrtf(var + 1e-5f);
    float* orow = out + (size_t)n * DD;
#pragma unroll
    for (int e = 0; e < 3; ++e) {
        float4 o;
        o.x = (v[e * 4 + 0] - mean) * rs;
        o.y = (v[e * 4 + 1] - mean) * rs;
        o.z = (v[e * 4 + 2] - mean) * rs;
        o.w = (v[e * 4 + 3] - mean) * rs;
        ((float4*)orow)[e * 64 + lane] = o;
    }
}

// ---------------- scores: out[row*2+which] = dot(pc[row>>5], cc[row]) / sqrt(CS) ----------------
__global__ __launch_bounds__(256) void score_dot(const ushort_t* __restrict__ pc,  // [256][512] bf16
                                                 const ushort_t* __restrict__ cc,  // [8192][512] bf16
                                                 float* __restrict__ out, int which) {
    const int wid = threadIdx.x >> 6;
    const int lane = threadIdx.x & 63;
    const int row = blockIdx.x * 4 + wid;
    const int b = row >> 5;
    const ushort_t* p = pc + (size_t)b * CSZ;
    const ushort_t* c = cc + (size_t)row * CSZ;
    float s = 0.f;
#pragma unroll
    for (int e = 0; e < 8; ++e) s += b2f(p[e * 64 + lane]) * b2f(c[e * 64 + lane]);
    s = wave_sum64(s);
    if (lane == 0) out[row * 2 + which] = s * 0.04419417382415922f; // 1/sqrt(512)
}

// ---------------- host launch ----------------
extern "C" void kernel_launch(void* const* d_in, const int* in_sizes, int n_in,
                              void* d_out, int out_size, void* d_ws, size_t ws_size,
                              hipStream_t stream) {
    const float* parent = (const float*)d_in[0];
    const float* child  = (const float*)d_in[1];
    const float* aiw = (const float*)d_in[4];
    const float* aib = (const float*)d_in[5];
    const float* aow = (const float*)d_in[6];
    const float* aob = (const float*)d_in[7];
    const float* l1w = (const float*)d_in[8];
    const float* l1b = (const float*)d_in[9];
    const float* l2w = (const float*)d_in[10];
    const float* l2b = (const float*)d_in[11];
    const float* pemb = (const float*)d_in[12];
    const float* pw1 = (const float*)d_in[13];
    const float* pb1 = (const float*)d_in[14];
    const float* pw2 = (const float*)d_in[15];
    const float* pb2 = (const float*)d_in[16];
    const float* lw1 = (const float*)d_in[17];
    const float* lb1 = (const float*)d_in[18];
    const float* lw2 = (const float*)d_in[19];
    const float* lb2 = (const float*)d_in[20];
    const float* rw1 = (const float*)d_in[21];
    const float* rb1 = (const float*)d_in[22];
    const float* rw2 = (const float*)d_in[23];
    const float* rb2 = (const float*)d_in[24];
    float* out = (float*)d_out;
    (void)in_sizes; (void)n_in; (void)out_size; (void)ws_size;

    // ---- workspace layout (ushort units unless noted); total ~175 MB ----
    ushort_t* W0 = (ushort_t*)d_ws;
    size_t off = 0;
    auto take = [&](size_t elems) { ushort_t* p = W0 + off; off += (elems + 127) & ~(size_t)127; return p; };
    ushort_t* aiw_b = take((size_t)LAYERS * 3 * DD * DD);   // 5,308,416
    ushort_t* aow_b = take((size_t)LAYERS * DD * DD);       // 1,769,472
    ushort_t* l1w_b = take((size_t)LAYERS * FFD * DD);      // 7,077,888
    ushort_t* l2w_b = take((size_t)LAYERS * DD * FFD);      // 7,077,888
    ushort_t* pw1_b = take((size_t)DD * DD);
    ushort_t* pw2_b = take((size_t)CSZ * DD);
    ushort_t* lw1_b = take((size_t)DD * DD);
    ushort_t* lw2_b = take((size_t)CSZ * DD);
    ushort_t* rw1_b = take((size_t)DD * DD);
    ushort_t* rw2_b = take((size_t)CSZ * DD);
    ushort_t* Pb    = take((size_t)NB * DD);                // parent bf16
    ushort_t* Xb    = take((size_t)NTOK * DD);              // residual stream bf16
    ushort_t* S1b   = take((size_t)CHROWS * FFD);           // QKV / FFN-hidden / child bf16
    ushort_t* S2b   = take((size_t)CHROWS * DD);            // attn out / MLP hidden
    ushort_t* S3b   = take((size_t)CHROWS * DD);            // delta / child-scores
    ushort_t* P1b   = take((size_t)NB * DD);
    ushort_t* P2b   = take((size_t)NB * CSZ);
    float* PEQ = (float*)(W0 + off); off += 2 * 3 * DD;     // fp32 [3][768]
    float* PEK = PEQ + 3 * DD;

    auto cvt = [&](const float* s, ushort_t* d, size_t n) {
        cvt_bf16<<<(int)((n + 1023) / 1024), 256, 0, stream>>>(s, d, (int)n);
    };
    auto gemm = [&](const ushort_t* A, int lda, const ushort_t* Wt, const float* bias,
                    ushort_t* C, int ldc, int M, int N, int K, int dg) {
        dim3 grid(N / 128, M / 128);
        gemm_bf16<<<grid, 256, 0, stream>>>(A, lda, Wt, bias, C, ldc, K, dg);
    };

    // ---- weight / input conversions ----
    cvt(aiw, aiw_b, (size_t)LAYERS * 3 * DD * DD);
    cvt(aow, aow_b, (size_t)LAYERS * DD * DD);
    cvt(l1w, l1w_b, (size_t)LAYERS * FFD * DD);
    cvt(l2w, l2w_b, (size_t)LAYERS * DD * FFD);
    cvt(pw1, pw1_b, (size_t)DD * DD);
    cvt(pw2, pw2_b, (size_t)CSZ * DD);
    cvt(lw1, lw1_b, (size_t)DD * DD);
    cvt(lw2, lw2_b, (size_t)CSZ * DD);
    cvt(rw1, rw1_b, (size_t)DD * DD);
    cvt(rw2, rw2_b, (size_t)CSZ * DD);
    cvt(parent, Pb, (size_t)NB * DD);
    cvt(child, S1b, (size_t)NB * NC * 2 * DD);              // child bf16 into S1b [16384][768]

    // ---- build x0 ----
    build_x<<<NTOK, 192, 0, stream>>>(parent, child, Xb);

    // ---- outside scores ----
    // parent chain: 256x768 -> gelu -> 256x512
    gemm(Pb, DD, pw1_b, pb1, P1b, DD, NB, DD, DD, 1);
    gemm(P1b, DD, pw2_b, pb2, P2b, CSZ, NB, CSZ, DD, 0);
    // left MLP on child[:,:,0,:] (even rows of S1b) -> right_score (which=1)
    gemm(S1b, 2 * DD, lw1_b, lb1, S2b, DD, NB * NC, DD, DD, 1);
    gemm(S2b, DD, lw2_b, lb2, S3b, CSZ, NB * NC, CSZ, DD, 0);
    score_dot<<<NB * NC / 4, 256, 0, stream>>>(P2b, S3b, out, 1);
    // right MLP on child[:,:,1,:] (odd rows) -> left_score (which=0)
    gemm(S1b + DD, 2 * DD, rw1_b, rb1, S2b, DD, NB * NC, DD, DD, 1);
    gemm(S2b, DD, rw2_b, rb2, S3b, CSZ, NB * NC, CSZ, DD, 0);
    score_dot<<<NB * NC / 4, 256, 0, stream>>>(P2b, S3b, out, 0);

    // ---- transformer layers ----
    for (int l = 0; l < LAYERS; ++l) {
        const ushort_t* Wl  = aiw_b + (size_t)l * 3 * DD * DD;
        const float* bl  = aib + (size_t)l * 3 * DD;
        const ushort_t* owl = aow_b + (size_t)l * DD * DD;
        const float* obl = aob + (size_t)l * DD;
        const ushort_t* w1l = l1w_b + (size_t)l * FFD * DD;
        const float* b1l = l1b + (size_t)l * FFD;
        const ushort_t* w2l = l2w_b + (size_t)l * DD * FFD;
        const float* b2l = l2b + (size_t)l * DD;

        // pe projections (fp32 weights/inputs)
        pe_proj<<<2 * 3 * DD / 4, 256, 0, stream>>>(pemb + (size_t)l * 4 * DD,
                                                    aiw + (size_t)l * 3 * DD * DD, PEQ, PEK);

        for (int c = 0; c < NCHUNK; ++c) {
            ushort_t* Xc = Xb + (size_t)c * CHROWS * DD;
            // QKV = x @ Wqkv^T + b -> S1b [8192][2304] bf16
            gemm(Xc, DD, Wl, bl, S1b, 3 * DD, CHROWS, 3 * DD, DD, 0);
            // attention -> S2b bf16
            attn_kernel<<<CHSEQ * NH / 4, 256, 0, stream>>>(S1b, PEQ, PEK, S2b, c * CHSEQ);
            // out-proj -> S3b bf16 delta
            gemm(S2b, DD, owl, obl, S3b, DD, CHROWS, DD, DD, 0);
            add_inorm<<<CHROWS / 4, 256, 0, stream>>>(Xc, S3b);
            // FFN
            gemm(Xc, DD, w1l, b1l, S1b, FFD, CHROWS, FFD, DD, 1);
            gemm(S1b, FFD, w2l, b2l, S3b, DD, CHROWS, DD, FFD, 0);
            add_inorm<<<CHROWS / 4, 256, 0, stream>>>(Xc, S3b);
        }
    }

    // ---- final: inorm over token-sum ----
    final_inorm<<<NSEQ / 4, 256, 0, stream>>>(Xb, out + NSEQ);
}

// Round 3
// 3064.088 us; speedup vs baseline: 8.0102x; 1.1437x over previous
//
#include <hip/hip_runtime.h>
#include <cstdint>
#include <cmath>

// ---------------- problem constants ----------------
#define DD      768
#define FFD     3072
#define NH      12
#define HDIM    64
#define LAYERS  3
#define CSZ     512
#define NB      256
#define NC      32
#define NSEQ    (NB * NC * 2)   // 16384 sequences
#define NTOK    (NSEQ * 2)      // 32768 token rows
#define CHROWS  8192            // token rows per chunk
#define NCHUNK  (NTOK / CHROWS) // 4
#define CHSEQ   (CHROWS / 2)    // 4096 sequences per chunk

typedef unsigned short ushort_t;
using short8 = __attribute__((ext_vector_type(8))) short;
using f32x4  = __attribute__((ext_vector_type(4))) float;

static __device__ __forceinline__ float b2f(ushort_t u) {
    union { float f; uint32_t i; } x; x.i = ((uint32_t)u) << 16; return x.f;
}
static __device__ __forceinline__ ushort_t f2b(float f) {
    uint32_t i = __float_as_uint(f);
    uint32_t r = (i + 0x7fffu + ((i >> 16) & 1u)) >> 16;   // RNE
    return (ushort_t)r;
}
static __device__ __forceinline__ float gelu_f(float x) {
    return 0.5f * x * (1.0f + erff(x * 0.70710678118654752f));
}
static __device__ __forceinline__ float wave_sum64(float v) {
#pragma unroll
    for (int off = 32; off > 0; off >>= 1) v += __shfl_xor(v, off, 64);
    return v;
}
static __device__ __forceinline__ void async_cp16(const void* g, void* l) {
    __builtin_amdgcn_global_load_lds((const __attribute__((address_space(1))) void*)g,
                                     (__attribute__((address_space(3))) void*)l, 16, 0, 0);
}

// ---------------- fp32 -> bf16 convert (n % 4 == 0) ----------------
__global__ __launch_bounds__(256) void cvt_bf16(const float* __restrict__ s,
                                                ushort_t* __restrict__ d, int n) {
    const int i = (blockIdx.x * 256 + threadIdx.x) * 4;
    if (i < n) {
        const float4 v = *(const float4*)(s + i);
        ushort4 o;
        o.x = f2b(v.x); o.y = f2b(v.y); o.z = f2b(v.z); o.w = f2b(v.w);
        *(ushort4*)(d + i) = o;
    }
}

// ---------------- build x0 (bf16): [32768][768] ----------------
__global__ __launch_bounds__(192) void build_x(const float* __restrict__ parent,
                                               const float* __restrict__ child,
                                               ushort_t* __restrict__ X) {
    const int r = blockIdx.x;
    const int t = threadIdx.x;        // 192 threads * 4 = 768
    const int n = r >> 1, q = r & 1;
    const int i = n >> 6;
    const int k = (n >> 1) & 31;
    const int j = n & 1;
    const float* src = (q == 0) ? (parent + (size_t)i * DD)
                                : (child + ((size_t)((i * 32 + k) * 2 + (1 - j))) * DD);
    const float4 v = ((const float4*)src)[t];
    ushort4 o;
    o.x = f2b(v.x); o.y = f2b(v.y); o.z = f2b(v.z); o.w = f2b(v.w);
    ((ushort4*)(X + (size_t)r * DD))[t] = o;
}

// ---------------- bf16 MFMA NT GEMM, swizzled 1-D grid, dbuf LDS ----------------
// C[M x N](bf16) = gelu?( A[M x K](bf16, lda) @ W[N x K]^T + bias(f32) )
// M,N multiples of 128; K multiple of 32. Grid = (M/128)*(N/128) blocks, 256 thr.
// Supertile order: GM x GN tiles clustered for L2 residency (GM | M/128, GN | N/128).
__global__ __launch_bounds__(256) void gemm_bf16(const ushort_t* __restrict__ A, int lda,
                                                 const ushort_t* __restrict__ W,
                                                 const float* __restrict__ bias,
                                                 ushort_t* __restrict__ C, int ldc,
                                                 int K, int NT, int GM, int GN,
                                                 int dogelu) {
    __shared__ __align__(16) short smem[16384];   // 32 KB: 2x(A 8KB) + 2x(B 8KB); reused by epilogue
    short* As = smem;                              // [2][4096]
    short* Bs = smem + 8192;                       // [2][4096]

    // ---- supertile swizzle ----
    const int st = blockIdx.x / (GM * GN);
    const int stn = NT / GN;
    const int srow = st / stn, scol = st - srow * stn;
    const int r = blockIdx.x - st * (GM * GN);
    const int mt = srow * GM + r / GN;
    const int nt = scol * GN + (r - (r / GN) * GN);
    const int m0 = mt * 128;
    const int n0 = nt * 128;

    const int tid = threadIdx.x;
    // staging: row = tid>>2 (0..63), col8 = (tid&3)*8
    const int r0s = tid >> 2, c0s = (tid & 3) * 8;
    const ushort_t* Ag0 = A + (size_t)(m0 + r0s) * lda + c0s;
    const ushort_t* Ag1 = A + (size_t)(m0 + 64 + r0s) * lda + c0s;
    const ushort_t* Wg0 = W + (size_t)(n0 + r0s) * K + c0s;
    const ushort_t* Wg1 = W + (size_t)(n0 + 64 + r0s) * K + c0s;

    const int wid = tid >> 6, lane = tid & 63;
    const int wm = (wid >> 1) * 64, wn = (wid & 1) * 64;
    const int lm = lane & 15;
    const int ko = (lane >> 4) * 8;

    f32x4 acc[4][4];
#pragma unroll
    for (int i = 0; i < 4; ++i)
#pragma unroll
        for (int j = 0; j < 4; ++j) acc[i][j] = {0.f, 0.f, 0.f, 0.f};

    // prologue: stage k0=0 into buffer 0
    {
        async_cp16(Ag0, As + tid * 8);
        async_cp16(Ag1, As + 2048 + tid * 8);
        async_cp16(Wg0, Bs + tid * 8);
        async_cp16(Wg1, Bs + 2048 + tid * 8);
    }

    for (int k0 = 0; k0 < K; k0 += 32) {
        const int b = (k0 >> 5) & 1;
        const int boff = b * 4096;
        __syncthreads();   // drains this wave's loads (vmcnt0) + syncs: buf b ready, buf b^1 free
        if (k0 + 32 < K) { // issue next tile into other buffer; overlapped by compute below
            const int o = (boff ^ 4096);
            const int k = k0 + 32;
            async_cp16(Ag0 + k, As + o + tid * 8);
            async_cp16(Ag1 + k, As + o + 2048 + tid * 8);
            async_cp16(Wg0 + k, Bs + o + tid * 8);
            async_cp16(Wg1 + k, Bs + o + 2048 + tid * 8);
        }
        short8 af[4], bfr[4];
#pragma unroll
        for (int i = 0; i < 4; ++i)
            af[i] = *(const short8*)(As + boff + (wm + i * 16 + lm) * 32 + ko);
#pragma unroll
        for (int j = 0; j < 4; ++j)
            bfr[j] = *(const short8*)(Bs + boff + (wn + j * 16 + lm) * 32 + ko);
#pragma unroll
        for (int i = 0; i < 4; ++i)
#pragma unroll
            for (int j = 0; j < 4; ++j)
                acc[i][j] = __builtin_amdgcn_mfma_f32_16x16x32_bf16(af[i], bfr[j], acc[i][j], 0, 0, 0);
    }

    // ---- epilogue: LDS transpose -> vectorized bf16 stores ----
    // Per quarter i (16 rows of the wave's 64x64 tile): write fp32 to LDS
    // (stride 68 words, <=2-way bank aliasing), read back row-major, store uint4.
    float* T = (float*)smem;                  // 8192 floats
    float* Tw = T + wid * 1088;               // 16*68 floats per wave
    const int r4 = lane >> 4;                 // write row-group
    const int rrow = lane >> 2;               // read row 0..15
    const int rc0 = (lane & 3) * 16;          // read col 0/16/32/48
    const int gcolb = n0 + wn;

    float4 bb[4];
    if (bias) {
#pragma unroll
        for (int t = 0; t < 4; ++t) bb[t] = *(const float4*)(bias + gcolb + rc0 + t * 4);
    } else {
#pragma unroll
        for (int t = 0; t < 4; ++t) bb[t] = make_float4(0.f, 0.f, 0.f, 0.f);
    }

#pragma unroll
    for (int i = 0; i < 4; ++i) {
        __syncthreads();   // region free (staging or previous quarter)
#pragma unroll
        for (int j = 0; j < 4; ++j)
#pragma unroll
            for (int rr = 0; rr < 4; ++rr)
                Tw[(r4 * 4 + rr) * 68 + j * 16 + lm] = acc[i][j][rr];
        __syncthreads();
        float o[16];
#pragma unroll
        for (int t = 0; t < 4; ++t)
            *(f32x4*)&o[t * 4] = *(const f32x4*)(Tw + rrow * 68 + rc0 + t * 4);
#pragma unroll
        for (int t = 0; t < 4; ++t) {
            o[t * 4 + 0] += ((const float*)&bb[t])[0];
            o[t * 4 + 1] += ((const float*)&bb[t])[1];
            o[t * 4 + 2] += ((const float*)&bb[t])[2];
            o[t * 4 + 3] += ((const float*)&bb[t])[3];
        }
        if (dogelu) {
#pragma unroll
            for (int t = 0; t < 16; ++t) o[t] = gelu_f(o[t]);
        }
        uint32_t pk[8];
#pragma unroll
        for (int t = 0; t < 8; ++t)
            pk[t] = (uint32_t)f2b(o[2 * t]) | ((uint32_t)f2b(o[2 * t + 1]) << 16);
        ushort_t* dst = C + (size_t)(m0 + wm + i * 16 + rrow) * ldc + gcolb + rc0;
        *(uint4*)dst = make_uint4(pk[0], pk[1], pk[2], pk[3]);
        *(uint4*)(dst + 8) = make_uint4(pk[4], pk[5], pk[6], pk[7]);
    }
}

// ---------------- pe projections: PEQ/PEK[r][o] = dot(pe[r], Wq/Wk[o]) ----------------
__global__ __launch_bounds__(256) void pe_proj(const float* __restrict__ pel,   // [4][768]
                                               const float* __restrict__ aiwl,  // [2304][768]
                                               float* __restrict__ PEQ,         // [3][768]
                                               float* __restrict__ PEK) {
    const int wid = threadIdx.x >> 6, lane = threadIdx.x & 63;
    const int task = blockIdx.x * 4 + wid;        // 0..4607
    const int which = task >= 3 * DD;
    const int idx = task - which * 3 * DD;
    const int r = idx / DD, o = idx - r * DD;
    const float* pe = pel + (size_t)r * DD;
    const float* w = aiwl + (size_t)(which ? DD + o : o) * DD;
    float s = 0.f;
#pragma unroll
    for (int e = 0; e < 12; ++e) s += pe[e * 64 + lane] * w[e * 64 + lane];
    s = wave_sum64(s);
    if (lane == 0) (which ? PEK : PEQ)[r * DD + o] = s;
}

// ---------------- attention (seq len 2), one wave per (sequence, head) ----------------
__global__ __launch_bounds__(256) void attn_kernel(const ushort_t* __restrict__ QKV, // [CHROWS][2304] bf16
                                                   const float* __restrict__ peq,
                                                   const float* __restrict__ pek,
                                                   ushort_t* __restrict__ O,         // [CHROWS][768] bf16
                                                   int seq0) {
    const int wid = threadIdx.x >> 6;
    const int lane = threadIdx.x & 63;
    const int task = blockIdx.x * 4 + wid;     // CHSEQ*NH tasks
    const int ns = task / NH;
    const int h = task - ns * NH;
    const int j = (seq0 + ns) & 1;
    const ushort_t* base = QKV + (size_t)(2 * ns) * (3 * DD);
    const int c = h * HDIM + lane;
    const int role1 = (1 + j) * DD;

    const float q0 = b2f(base[c]) + peq[c];
    const float k0 = b2f(base[DD + c]) + pek[c];
    const float v0 = b2f(base[2 * DD + c]);
    const ushort_t* base1 = base + 3 * DD;
    const float q1 = b2f(base1[c]) + peq[role1 + c];
    const float k1 = b2f(base1[DD + c]) + pek[role1 + c];
    const float v1 = b2f(base1[2 * DD + c]);

    float p00 = q0 * k0, p01 = q0 * k1, p10 = q1 * k0, p11 = q1 * k1;
#pragma unroll
    for (int off = 32; off > 0; off >>= 1) {
        p00 += __shfl_xor(p00, off, 64);
        p01 += __shfl_xor(p01, off, 64);
        p10 += __shfl_xor(p10, off, 64);
        p11 += __shfl_xor(p11, off, 64);
    }
    const float sc = 0.125f;
    const float s00 = p00 * sc, s01 = p01 * sc, s10 = p10 * sc, s11 = p11 * sc;

    const float m0 = fmaxf(s00, s01);
    const float e00 = __expf(s00 - m0), e01 = __expf(s01 - m0);
    const float a00 = e00 / (e00 + e01);
    const float o0 = a00 * v0 + (1.0f - a00) * v1;

    const float m1 = fmaxf(s10, s11);
    const float e10 = __expf(s10 - m1), e11 = __expf(s11 - m1);
    const float a10 = e10 / (e10 + e11);
    const float o1 = a10 * v0 + (1.0f - a10) * v1;

    O[(size_t)(2 * ns) * DD + c] = f2b(o0);
    O[(size_t)(2 * ns + 1) * DD + c] = f2b(o1);
}

// ---------------- x = inorm(x + d), bf16 in/out, one wave per row ----------------
__global__ __launch_bounds__(256) void add_inorm(ushort_t* __restrict__ x,
                                                 const ushort_t* __restrict__ d) {
    const int wid = threadIdx.x >> 6, lane = threadIdx.x & 63;
    const int r = blockIdx.x * 4 + wid;
    ushort_t* xr = x + (size_t)r * DD;
    const ushort_t* dr = d + (size_t)r * DD;
    float v[12];
    float s = 0.f, ss = 0.f;
#pragma unroll
    for (int e = 0; e < 3; ++e) {
        const ushort4 xa = ((const ushort4*)xr)[e * 64 + lane];
        const ushort4 da = ((const ushort4*)dr)[e * 64 + lane];
        const float a0 = b2f(xa.x) + b2f(da.x);
        const float a1 = b2f(xa.y) + b2f(da.y);
        const float a2 = b2f(xa.z) + b2f(da.z);
        const float a3 = b2f(xa.w) + b2f(da.w);
        v[e * 4 + 0] = a0; v[e * 4 + 1] = a1; v[e * 4 + 2] = a2; v[e * 4 + 3] = a3;
        s += a0 + a1 + a2 + a3;
        ss += a0 * a0 + a1 * a1 + a2 * a2 + a3 * a3;
    }
    s = wave_sum64(s); ss = wave_sum64(ss);
    const float mean = s * (1.0f / DD);
    const float var = ss * (1.0f / DD) - mean * mean;
    const float rs = rsqrtf(var + 1e-5f);
#pragma unroll
    for (int e = 0; e < 3; ++e) {
        ushort4 o;
        o.x = f2b((v[e * 4 + 0] - mean) * rs);
        o.y = f2b((v[e * 4 + 1] - mean) * rs);
        o.z = f2b((v[e * 4 + 2] - mean) * rs);
        o.w = f2b((v[e * 4 + 3] - mean) * rs);
        ((ushort4*)xr)[e * 64 + lane] = o;
    }
}

// ---------------- final: out[n] = inorm(x[2n] + x[2n+1]) fp32 out, wave per row ----------------
__global__ __launch_bounds__(256) void final_inorm(const ushort_t* __restrict__ x,
                                                   float* __restrict__ out) {
    const int wid = threadIdx.x >> 6, lane = threadIdx.x & 63;
    const int n = blockIdx.x * 4 + wid;
    const ushort_t* r0 = x + (size_t)(2 * n) * DD;
    const ushort_t* r1 = r0 + DD;
    float v[12];
    float s = 0.f, ss = 0.f;
#pragma unroll
    for (int e = 0; e < 3; ++e) {
        const ushort4 xa = ((const ushort4*)r0)[e * 64 + lane];
        const ushort4 xb = ((const ushort4*)r1)[e * 64 + lane];
        const float a0 = b2f(xa.x) + b2f(xb.x);
        const float a1 = b2f(xa.y) + b2f(xb.y);
        const float a2 = b2f(xa.z) + b2f(xb.z);
        const float a3 = b2f(xa.w) + b2f(xb.w);
        v[e * 4 + 0] = a0; v[e * 4 + 1] = a1; v[e * 4 + 2] = a2; v[e * 4 + 3] = a3;
        s += a0 + a1 + a2 + a3;
        ss += a0 * a0 + a1 * a1 + a2 * a2 + a3 * a3;
    }
    s = wave_sum64(s); ss = wave_sum64(ss);
    const float mean = s * (1.0f / DD);
    const float var = ss * (1.0f / DD) - mean * mean;
    const float rs = rsqrtf(var + 1e-5f);
    float* orow = out + (size_t)n * DD;
#pragma unroll
    for (int e = 0; e < 3; ++e) {
        float4 o;
        o.x = (v[e * 4 + 0] - mean) * rs;
        o.y = (v[e * 4 + 1] - mean) * rs;
        o.z = (v[e * 4 + 2] - mean) * rs;
        o.w = (v[e * 4 + 3] - mean) * rs;
        ((float4*)orow)[e * 64 + lane] = o;
    }
}

// ---------------- scores: out[row*2+which] = dot(pc[row>>5], cc[row]) / sqrt(CS) ----------------
__global__ __launch_bounds__(256) void score_dot(const ushort_t* __restrict__ pc,  // [256][512] bf16
                                                 const ushort_t* __restrict__ cc,  // [8192][512] bf16
                                                 float* __restrict__ out, int which) {
    const int wid = threadIdx.x >> 6;
    const int lane = threadIdx.x & 63;
    const int row = blockIdx.x * 4 + wid;
    const int b = row >> 5;
    const ushort_t* p = pc + (size_t)b * CSZ;
    const ushort_t* c = cc + (size_t)row * CSZ;
    float s = 0.f;
#pragma unroll
    for (int e = 0; e < 8; ++e) s += b2f(p[e * 64 + lane]) * b2f(c[e * 64 + lane]);
    s = wave_sum64(s);
    if (lane == 0) out[row * 2 + which] = s * 0.04419417382415922f; // 1/sqrt(512)
}

// ---------------- host launch ----------------
extern "C" void kernel_launch(void* const* d_in, const int* in_sizes, int n_in,
                              void* d_out, int out_size, void* d_ws, size_t ws_size,
                              hipStream_t stream) {
    const float* parent = (const float*)d_in[0];
    const float* child  = (const float*)d_in[1];
    const float* aiw = (const float*)d_in[4];
    const float* aib = (const float*)d_in[5];
    const float* aow = (const float*)d_in[6];
    const float* aob = (const float*)d_in[7];
    const float* l1w = (const float*)d_in[8];
    const float* l1b = (const float*)d_in[9];
    const float* l2w = (const float*)d_in[10];
    const float* l2b = (const float*)d_in[11];
    const float* pemb = (const float*)d_in[12];
    const float* pw1 = (const float*)d_in[13];
    const float* pb1 = (const float*)d_in[14];
    const float* pw2 = (const float*)d_in[15];
    const float* pb2 = (const float*)d_in[16];
    const float* lw1 = (const float*)d_in[17];
    const float* lb1 = (const float*)d_in[18];
    const float* lw2 = (const float*)d_in[19];
    const float* lb2 = (const float*)d_in[20];
    const float* rw1 = (const float*)d_in[21];
    const float* rb1 = (const float*)d_in[22];
    const float* rw2 = (const float*)d_in[23];
    const float* rb2 = (const float*)d_in[24];
    float* out = (float*)d_out;
    (void)in_sizes; (void)n_in; (void)out_size; (void)ws_size;

    // ---- workspace layout (ushort units unless noted); total ~175 MB ----
    ushort_t* W0 = (ushort_t*)d_ws;
    size_t off = 0;
    auto take = [&](size_t elems) { ushort_t* p = W0 + off; off += (elems + 127) & ~(size_t)127; return p; };
    ushort_t* aiw_b = take((size_t)LAYERS * 3 * DD * DD);
    ushort_t* aow_b = take((size_t)LAYERS * DD * DD);
    ushort_t* l1w_b = take((size_t)LAYERS * FFD * DD);
    ushort_t* l2w_b = take((size_t)LAYERS * DD * FFD);
    ushort_t* pw1_b = take((size_t)DD * DD);
    ushort_t* pw2_b = take((size_t)CSZ * DD);
    ushort_t* lw1_b = take((size_t)DD * DD);
    ushort_t* lw2_b = take((size_t)CSZ * DD);
    ushort_t* rw1_b = take((size_t)DD * DD);
    ushort_t* rw2_b = take((size_t)CSZ * DD);
    ushort_t* Pb    = take((size_t)NB * DD);
    ushort_t* Xb    = take((size_t)NTOK * DD);
    ushort_t* S1b   = take((size_t)CHROWS * FFD);
    ushort_t* S2b   = take((size_t)CHROWS * DD);
    ushort_t* S3b   = take((size_t)CHROWS * DD);
    ushort_t* P1b   = take((size_t)NB * DD);
    ushort_t* P2b   = take((size_t)NB * CSZ);
    float* PEQ = (float*)(W0 + off); off += 2 * 3 * DD;
    float* PEK = PEQ + 3 * DD;

    auto cvt = [&](const float* s, ushort_t* d, size_t n) {
        cvt_bf16<<<(int)((n + 1023) / 1024), 256, 0, stream>>>(s, d, (int)n);
    };
    auto gemm = [&](const ushort_t* A, int lda, const ushort_t* Wt, const float* bias,
                    ushort_t* C, int ldc, int M, int N, int K, int dg) {
        const int MT = M / 128, NT = N / 128;
        const int GM = (MT % 8 == 0) ? 8 : MT;
        int GN = 8;
        while (NT % GN) --GN;            // largest divisor of NT that is <= 8
        gemm_bf16<<<MT * NT, 256, 0, stream>>>(A, lda, Wt, bias, C, ldc, K, NT, GM, GN, dg);
    };

    // ---- weight / input conversions ----
    cvt(aiw, aiw_b, (size_t)LAYERS * 3 * DD * DD);
    cvt(aow, aow_b, (size_t)LAYERS * DD * DD);
    cvt(l1w, l1w_b, (size_t)LAYERS * FFD * DD);
    cvt(l2w, l2w_b, (size_t)LAYERS * DD * FFD);
    cvt(pw1, pw1_b, (size_t)DD * DD);
    cvt(pw2, pw2_b, (size_t)CSZ * DD);
    cvt(lw1, lw1_b, (size_t)DD * DD);
    cvt(lw2, lw2_b, (size_t)CSZ * DD);
    cvt(rw1, rw1_b, (size_t)DD * DD);
    cvt(rw2, rw2_b, (size_t)CSZ * DD);
    cvt(parent, Pb, (size_t)NB * DD);
    cvt(child, S1b, (size_t)NB * NC * 2 * DD);   // child bf16 into S1b [16384][768]

    // ---- build x0 ----
    build_x<<<NTOK, 192, 0, stream>>>(parent, child, Xb);

    // ---- outside scores ----
    gemm(Pb, DD, pw1_b, pb1, P1b, DD, NB, DD, DD, 1);
    gemm(P1b, DD, pw2_b, pb2, P2b, CSZ, NB, CSZ, DD, 0);
    gemm(S1b, 2 * DD, lw1_b, lb1, S2b, DD, NB * NC, DD, DD, 1);
    gemm(S2b, DD, lw2_b, lb2, S3b, CSZ, NB * NC, CSZ, DD, 0);
    score_dot<<<NB * NC / 4, 256, 0, stream>>>(P2b, S3b, out, 1);
    gemm(S1b + DD, 2 * DD, rw1_b, rb1, S2b, DD, NB * NC, DD, DD, 1);
    gemm(S2b, DD, rw2_b, rb2, S3b, CSZ, NB * NC, CSZ, DD, 0);
    score_dot<<<NB * NC / 4, 256, 0, stream>>>(P2b, S3b, out, 0);

    // ---- transformer layers ----
    for (int l = 0; l < LAYERS; ++l) {
        const ushort_t* Wl  = aiw_b + (size_t)l * 3 * DD * DD;
        const float* bl  = aib + (size_t)l * 3 * DD;
        const ushort_t* owl = aow_b + (size_t)l * DD * DD;
        const float* obl = aob + (size_t)l * DD;
        const ushort_t* w1l = l1w_b + (size_t)l * FFD * DD;
        const float* b1l = l1b + (size_t)l * FFD;
        const ushort_t* w2l = l2w_b + (size_t)l * DD * FFD;
        const float* b2l = l2b + (size_t)l * DD;

        pe_proj<<<2 * 3 * DD / 4, 256, 0, stream>>>(pemb + (size_t)l * 4 * DD,
                                                    aiw + (size_t)l * 3 * DD * DD, PEQ, PEK);

        for (int c = 0; c < NCHUNK; ++c) {
            ushort_t* Xc = Xb + (size_t)c * CHROWS * DD;
            gemm(Xc, DD, Wl, bl, S1b, 3 * DD, CHROWS, 3 * DD, DD, 0);
            attn_kernel<<<CHSEQ * NH / 4, 256, 0, stream>>>(S1b, PEQ, PEK, S2b, c * CHSEQ);
            gemm(S2b, DD, owl, obl, S3b, DD, CHROWS, DD, DD, 0);
            add_inorm<<<CHROWS / 4, 256, 0, stream>>>(Xc, S3b);
            gemm(Xc, DD, w1l, b1l, S1b, FFD, CHROWS, FFD, DD, 1);
            gemm(S1b, FFD, w2l, b2l, S3b, DD, CHROWS, DD, FFD, 0);
            add_inorm<<<CHROWS / 4, 256, 0, stream>>>(Xc, S3b);
        }
    }

    // ---- final: inorm over token-sum ----
    final_inorm<<<NSEQ / 4, 256, 0, stream>>>(Xb, out + NSEQ);
}